// Round 1
// baseline (306.102 us; speedup 1.0000x reference)
//
#include <hip/hip_runtime.h>

// NGP multiresolution hash-grid interpolation encoding.
// B=262144 points, DIM=3, L=16 levels, T=19 (2^19 table entries/level), F=2.
// thread = b*16 + l: 16 lanes share one point's coords (L1 broadcast),
// float2 output store is perfectly coalesced (512B/wave).

#define NB 262144
#define NL 16
#define TSIZE (1u << 19)
#define TMASK ((1u << 19) - 1u)
#define P1 2654435761u
#define P2 805459861u

// floor(16 * b^l), b = exp(ln(32)/15) = 2^(1/3): canonical instant-NGP ladder.
__constant__ float RES_C[NL] = {16.f, 20.f, 25.f, 32.f, 40.f, 50.f, 64.f, 80.f,
                                101.f, 128.f, 161.f, 203.f, 256.f, 322.f, 406.f, 512.f};

__global__ __launch_bounds__(256) void ngp_interp_kernel(
    const float* __restrict__ x,       // (B, 3)
    const float* __restrict__ tables,  // (L, 2^19, 2)
    float* __restrict__ out) {         // (B, L*2)
  const int tid = blockIdx.x * blockDim.x + threadIdx.x;  // b*16 + l
  const int l = tid & (NL - 1);
  const int b = tid >> 4;

  const float res = RES_C[l];
  const float sx = x[b * 3 + 0] * res;
  const float sy = x[b * 3 + 1] * res;
  const float sz = x[b * 3 + 2] * res;

  const float fx = floorf(sx), fy = floorf(sy), fz = floorf(sz);
  const unsigned ix = (unsigned)fx, iy = (unsigned)fy, iz = (unsigned)fz;

  // hash components; (i+1)*P = i*P + P
  const unsigned hx0 = ix;            // prime 1
  const unsigned hx1 = ix + 1u;
  const unsigned hy0 = iy * P1;
  const unsigned hy1 = hy0 + P1;
  const unsigned hz0 = iz * P2;
  const unsigned hz1 = hz0 + P2;

  // weights exactly as reference: 1 - |scaled - float(grid)|
  const float wx0 = 1.0f - fabsf(sx - fx);
  const float wx1 = 1.0f - fabsf(sx - (fx + 1.0f));
  const float wy0 = 1.0f - fabsf(sy - fy);
  const float wy1 = 1.0f - fabsf(sy - (fy + 1.0f));
  const float wz0 = 1.0f - fabsf(sz - fz);
  const float wz1 = 1.0f - fabsf(sz - (fz + 1.0f));

  const float2* __restrict__ tbl = (const float2*)tables + (size_t)l * TSIZE;

  // compute all 8 indices first so the compiler can issue all 8 gathers
  unsigned idxs[8];
#pragma unroll
  for (int v = 0; v < 8; ++v) {
    const unsigned hx = (v & 1) ? hx1 : hx0;
    const unsigned hy = (v & 2) ? hy1 : hy0;
    const unsigned hz = (v & 4) ? hz1 : hz0;
    idxs[v] = (hx ^ hy ^ hz) & TMASK;
  }
  float2 g[8];
#pragma unroll
  for (int v = 0; v < 8; ++v) g[v] = tbl[idxs[v]];

  float o0 = 0.0f, o1 = 0.0f;
#pragma unroll
  for (int v = 0; v < 8; ++v) {
    const float w = ((v & 1) ? wx1 : wx0) * ((v & 2) ? wy1 : wy0) * ((v & 4) ? wz1 : wz0);
    o0 = fmaf(w, g[v].x, o0);
    o1 = fmaf(w, g[v].y, o1);
  }

  ((float2*)out)[tid] = make_float2(o0, o1);
}

extern "C" void kernel_launch(void* const* d_in, const int* in_sizes, int n_in,
                              void* d_out, int out_size, void* d_ws, size_t ws_size,
                              hipStream_t stream) {
  const float* x = (const float*)d_in[0];       // B*3 floats
  const float* tables = (const float*)d_in[1];  // 16*524288*2 floats
  float* out = (float*)d_out;                   // B*32 floats

  const int total = NB * NL;  // 4,194,304 threads
  const int block = 256;
  const int grid = total / block;  // 16384
  ngp_interp_kernel<<<grid, block, 0, stream>>>(x, tables, out);
}

// Round 3
// 200.350 us; speedup vs baseline: 1.5278x; 1.5278x over previous
//
#include <hip/hip_runtime.h>

// NGP multiresolution hash-grid interpolation encoding.
// B=262144 points, DIM=3, L=16 levels, T=19 (2^19 entries/level), F=2.
//
// R1 strategy (R2 = compile fix: native ext_vector_type for nontemporal ops):
//   phase 1: block = 256 points x 1 level. level = (blockIdx&7) + 8*(blockIdx>>13)
//            -> all blocks of level l land on XCD l%8 (round-robin dispatch
//            heuristic), and levels 0-7 run before 8-15, so each XCD's 4 MiB L2
//            holds exactly one 4 MiB table at a time. Output goes to a
//            level-major workspace (coalesced, no false sharing).
//   phase 2: LDS-tiled transpose ws[l][b] -> out[b][l] (pure streaming).
// x / ws traffic uses nontemporal ops to keep table lines resident in L2.

#define NB 262144
#define NL 16
#define TSIZE (1u << 19)
#define TMASK ((1u << 19) - 1u)
#define P1 2654435761u
#define P2 805459861u

typedef float vf2 __attribute__((ext_vector_type(2)));
typedef float vf4 __attribute__((ext_vector_type(4)));

__constant__ float RES_C[NL] = {16.f, 20.f, 25.f, 32.f, 40.f, 50.f, 64.f, 80.f,
                                101.f, 128.f, 161.f, 203.f, 256.f, 322.f, 406.f, 512.f};

__device__ __forceinline__ void ngp_point_level(
    float px, float py, float pz, int l, const float* __restrict__ tables,
    float& o0, float& o1) {
  const float res = RES_C[l];
  const float sx = px * res, sy = py * res, sz = pz * res;
  const float fx = floorf(sx), fy = floorf(sy), fz = floorf(sz);
  const unsigned ix = (unsigned)fx, iy = (unsigned)fy, iz = (unsigned)fz;

  const unsigned hx0 = ix, hx1 = ix + 1u;
  const unsigned hy0 = iy * P1, hy1 = hy0 + P1;
  const unsigned hz0 = iz * P2, hz1 = hz0 + P2;

  const float wx0 = 1.0f - fabsf(sx - fx);
  const float wx1 = 1.0f - fabsf(sx - (fx + 1.0f));
  const float wy0 = 1.0f - fabsf(sy - fy);
  const float wy1 = 1.0f - fabsf(sy - (fy + 1.0f));
  const float wz0 = 1.0f - fabsf(sz - fz);
  const float wz1 = 1.0f - fabsf(sz - (fz + 1.0f));

  const vf2* __restrict__ tbl = (const vf2*)tables + (size_t)l * TSIZE;

  unsigned idxs[8];
#pragma unroll
  for (int v = 0; v < 8; ++v) {
    const unsigned hx = (v & 1) ? hx1 : hx0;
    const unsigned hy = (v & 2) ? hy1 : hy0;
    const unsigned hz = (v & 4) ? hz1 : hz0;
    idxs[v] = (hx ^ hy ^ hz) & TMASK;
  }
  vf2 g[8];
#pragma unroll
  for (int v = 0; v < 8; ++v) g[v] = tbl[idxs[v]];

  o0 = 0.0f; o1 = 0.0f;
#pragma unroll
  for (int v = 0; v < 8; ++v) {
    const float w = ((v & 1) ? wx1 : wx0) * ((v & 2) ? wy1 : wy0) * ((v & 4) ? wz1 : wz0);
    o0 = fmaf(w, g[v].x, o0);
    o1 = fmaf(w, g[v].y, o1);
  }
}

// ---- phase 1: level-specialized gather into level-major workspace ----
__global__ __launch_bounds__(256) void ngp_gather_kernel(
    const float* __restrict__ x,       // (B, 3)
    const float* __restrict__ tables,  // (L, 2^19, 2)
    vf2* __restrict__ ws) {            // (L, B)
  const int i = blockIdx.x;                       // 0..16383
  const int lvl = (i & 7) | ((i >> 13) << 3);     // XCD swizzle + 2 temporal phases
  const int chunk = (i >> 3) & 1023;
  const int b = chunk * 256 + threadIdx.x;

  // nontemporal: keep x out of L2 (table lines are the precious ones)
  const float px = __builtin_nontemporal_load(x + b * 3 + 0);
  const float py = __builtin_nontemporal_load(x + b * 3 + 1);
  const float pz = __builtin_nontemporal_load(x + b * 3 + 2);

  float o0, o1;
  ngp_point_level(px, py, pz, lvl, tables, o0, o1);

  vf2 r; r.x = o0; r.y = o1;
  __builtin_nontemporal_store(r, ws + (size_t)lvl * NB + b);
}

// ---- phase 2: transpose ws[l][b] -> out[b][l*2+f], streaming ----
__global__ __launch_bounds__(256) void ngp_transpose_kernel(
    const vf2* __restrict__ ws,  // (L, B)
    vf4* __restrict__ out4) {    // (B, 8) float4 view of (B, 32) floats
  __shared__ vf2 tile[NL][257];  // pad: bank-conflict-light
  const int t = threadIdx.x;
  const int p0 = blockIdx.x * 256;

#pragma unroll
  for (int l = 0; l < NL; ++l) {
    tile[l][t] = __builtin_nontemporal_load(ws + (size_t)l * NB + p0 + t);
  }
  __syncthreads();

  // linear coalesced write: q = k*256 + t indexes float4s of this block's out chunk
#pragma unroll
  for (int k = 0; k < 8; ++k) {
    const int q = k * 256 + t;
    const int pq = q >> 3;        // point within block
    const int wq = q & 7;         // which float4 of the point (2 levels)
    const vf2 a = tile[2 * wq + 0][pq];
    const vf2 c = tile[2 * wq + 1][pq];
    vf4 v; v.x = a.x; v.y = a.y; v.z = c.x; v.w = c.y;
    __builtin_nontemporal_store(v, out4 + (size_t)p0 * 8 + q);
  }
}

// ---- fallback (R0 kernel) if workspace too small ----
__global__ __launch_bounds__(256) void ngp_fused_kernel(
    const float* __restrict__ x, const float* __restrict__ tables,
    float* __restrict__ out) {
  const int tid = blockIdx.x * blockDim.x + threadIdx.x;
  const int l = tid & (NL - 1);
  const int b = tid >> 4;
  float o0, o1;
  ngp_point_level(x[b * 3], x[b * 3 + 1], x[b * 3 + 2], l, tables, o0, o1);
  float2 r = make_float2(o0, o1);
  ((float2*)out)[tid] = r;
}

extern "C" void kernel_launch(void* const* d_in, const int* in_sizes, int n_in,
                              void* d_out, int out_size, void* d_ws, size_t ws_size,
                              hipStream_t stream) {
  const float* x = (const float*)d_in[0];
  const float* tables = (const float*)d_in[1];
  float* out = (float*)d_out;

  const size_t ws_needed = (size_t)NL * NB * sizeof(vf2);  // 32 MB
  if (ws_size >= ws_needed) {
    vf2* ws = (vf2*)d_ws;
    ngp_gather_kernel<<<NB * NL / 256, 256, 0, stream>>>(x, tables, ws);
    ngp_transpose_kernel<<<NB / 256, 256, 0, stream>>>(ws, (vf4*)out);
  } else {
    ngp_fused_kernel<<<NB * NL / 256, 256, 0, stream>>>(x, tables, out);
  }
}

// Round 4
// 196.493 us; speedup vs baseline: 1.5578x; 1.0196x over previous
//
#include <hip/hip_runtime.h>

// NGP multiresolution hash-grid interpolation encoding.
// B=262144 points, DIM=3, L=16 levels, T=19 (2^19 entries/level), F=2.
//
// R3 structure (kept): level-specialized blocks + XCD pinning; level-major
// workspace; LDS transpose phase (measured ~7us — not the bottleneck).
// R4 change: x-corner pairing. hash = ix ^ iy*P1 ^ iz*P2, so for even ix the
// two x-adjacent corners live at table indices {idx, idx^1} -> one aligned
// 16B dwordx4 serves both. Even-ix points: 4 requests instead of 8.
// Average L2 request count drops 25% (the measured bottleneck: 33.5M random
// 8B gathers at the ~2.3TB/s effective L2 random-gather ceiling = 105us).

#define NB 262144
#define NL 16
#define TSIZE (1u << 19)
#define TMASK ((1u << 19) - 1u)
#define P1 2654435761u
#define P2 805459861u

typedef float vf2 __attribute__((ext_vector_type(2)));
typedef float vf4 __attribute__((ext_vector_type(4)));

__constant__ float RES_C[NL] = {16.f, 20.f, 25.f, 32.f, 40.f, 50.f, 64.f, 80.f,
                                101.f, 128.f, 161.f, 203.f, 256.f, 322.f, 406.f, 512.f};

__device__ __forceinline__ void ngp_point_level(
    float px, float py, float pz, int l, const float* __restrict__ tables,
    float& o0, float& o1) {
  const float res = RES_C[l];
  const float sx = px * res, sy = py * res, sz = pz * res;
  const float fx = floorf(sx), fy = floorf(sy), fz = floorf(sz);
  const unsigned ix = (unsigned)fx, iy = (unsigned)fy, iz = (unsigned)fz;

  const unsigned hy0 = iy * P1, hy1 = hy0 + P1;
  const unsigned hz0 = iz * P2, hz1 = hz0 + P2;

  const float wx0 = 1.0f - fabsf(sx - fx);
  const float wx1 = 1.0f - fabsf(sx - (fx + 1.0f));
  const float wy0 = 1.0f - fabsf(sy - fy);
  const float wy1 = 1.0f - fabsf(sy - (fy + 1.0f));
  const float wz0 = 1.0f - fabsf(sz - fz);
  const float wz1 = 1.0f - fabsf(sz - (fz + 1.0f));

  const vf2* __restrict__ tbl2 = (const vf2*)tables + (size_t)l * TSIZE;
  const vf4* __restrict__ tbl4 = (const vf4*)tables + (size_t)l * (TSIZE / 2);

  // yz hash combos, p = ybit + 2*zbit (matches v = xbit + 2*ybit + 4*zbit)
  unsigned hyz[4];
  hyz[0] = hy0 ^ hz0;
  hyz[1] = hy1 ^ hz0;
  hyz[2] = hy0 ^ hz1;
  hyz[3] = hy1 ^ hz1;

  vf2 g[8];  // g[v], v = xbit + 2*ybit + 4*zbit
  if ((ix & 1u) == 0u) {
    // even ix: x1 corner index = x0 index ^ 1 -> both corners in one aligned
    // 16B pair {i0 & ~1, i0 | 1}.
#pragma unroll
    for (int p = 0; p < 4; ++p) {
      const unsigned i0 = (ix ^ hyz[p]) & TMASK;
      const vf4 q = tbl4[i0 >> 1];
      vf2 lo; lo.x = q.x; lo.y = q.y;
      vf2 hi; hi.x = q.z; hi.y = q.w;
      const bool x0_is_lo = (i0 & 1u) == 0u;
      g[2 * p + 0] = x0_is_lo ? lo : hi;
      g[2 * p + 1] = x0_is_lo ? hi : lo;
    }
  } else {
#pragma unroll
    for (int p = 0; p < 4; ++p) {
      const unsigned i0 = (ix ^ hyz[p]) & TMASK;
      const unsigned i1 = ((ix + 1u) ^ hyz[p]) & TMASK;
      g[2 * p + 0] = tbl2[i0];
      g[2 * p + 1] = tbl2[i1];
    }
  }

  o0 = 0.0f; o1 = 0.0f;
#pragma unroll
  for (int v = 0; v < 8; ++v) {
    const float w = ((v & 1) ? wx1 : wx0) * ((v & 2) ? wy1 : wy0) * ((v & 4) ? wz1 : wz0);
    o0 = fmaf(w, g[v].x, o0);
    o1 = fmaf(w, g[v].y, o1);
  }
}

// ---- phase 1: level-specialized gather into level-major workspace ----
__global__ __launch_bounds__(256) void ngp_gather_kernel(
    const float* __restrict__ x,       // (B, 3)
    const float* __restrict__ tables,  // (L, 2^19, 2)
    vf2* __restrict__ ws) {            // (L, B)
  const int i = blockIdx.x;                       // 0..16383
  const int lvl = (i & 7) | ((i >> 13) << 3);     // XCD swizzle + 2 temporal phases
  const int chunk = (i >> 3) & 1023;
  const int b = chunk * 256 + threadIdx.x;

  const float px = __builtin_nontemporal_load(x + b * 3 + 0);
  const float py = __builtin_nontemporal_load(x + b * 3 + 1);
  const float pz = __builtin_nontemporal_load(x + b * 3 + 2);

  float o0, o1;
  ngp_point_level(px, py, pz, lvl, tables, o0, o1);

  vf2 r; r.x = o0; r.y = o1;
  __builtin_nontemporal_store(r, ws + (size_t)lvl * NB + b);
}

// ---- phase 2: transpose ws[l][b] -> out[b][l*2+f], streaming ----
__global__ __launch_bounds__(256) void ngp_transpose_kernel(
    const vf2* __restrict__ ws,  // (L, B)
    vf4* __restrict__ out4) {    // (B, 8) float4 view of (B, 32) floats
  __shared__ vf2 tile[NL][257];
  const int t = threadIdx.x;
  const int p0 = blockIdx.x * 256;

#pragma unroll
  for (int l = 0; l < NL; ++l) {
    tile[l][t] = __builtin_nontemporal_load(ws + (size_t)l * NB + p0 + t);
  }
  __syncthreads();

#pragma unroll
  for (int k = 0; k < 8; ++k) {
    const int q = k * 256 + t;
    const int pq = q >> 3;
    const int wq = q & 7;
    const vf2 a = tile[2 * wq + 0][pq];
    const vf2 c = tile[2 * wq + 1][pq];
    vf4 v; v.x = a.x; v.y = a.y; v.z = c.x; v.w = c.y;
    __builtin_nontemporal_store(v, out4 + (size_t)p0 * 8 + q);
  }
}

// ---- fallback if workspace too small ----
__global__ __launch_bounds__(256) void ngp_fused_kernel(
    const float* __restrict__ x, const float* __restrict__ tables,
    float* __restrict__ out) {
  const int tid = blockIdx.x * blockDim.x + threadIdx.x;
  const int l = tid & (NL - 1);
  const int b = tid >> 4;
  float o0, o1;
  ngp_point_level(x[b * 3], x[b * 3 + 1], x[b * 3 + 2], l, tables, o0, o1);
  float2 r = make_float2(o0, o1);
  ((float2*)out)[tid] = r;
}

extern "C" void kernel_launch(void* const* d_in, const int* in_sizes, int n_in,
                              void* d_out, int out_size, void* d_ws, size_t ws_size,
                              hipStream_t stream) {
  const float* x = (const float*)d_in[0];
  const float* tables = (const float*)d_in[1];
  float* out = (float*)d_out;

  const size_t ws_needed = (size_t)NL * NB * sizeof(vf2);  // 32 MB
  if (ws_size >= ws_needed) {
    vf2* ws = (vf2*)d_ws;
    ngp_gather_kernel<<<NB * NL / 256, 256, 0, stream>>>(x, tables, ws);
    ngp_transpose_kernel<<<NB / 256, 256, 0, stream>>>(ws, (vf4*)out);
  } else {
    ngp_fused_kernel<<<NB * NL / 256, 256, 0, stream>>>(x, tables, out);
  }
}